// Round 1
// baseline (1224.295 us; speedup 1.0000x reference)
//
#include <hip/hip_runtime.h>

// HeteroGraphSage: 2-layer SAGEConv(mean) + per-channel PReLU + input-skip.
// N=100000 nodes, IN=D=64, E=1600000 edges, fp32.

__global__ __launch_bounds__(256) void scatter_kernel(
    const int* __restrict__ src, const int* __restrict__ dst,
    const float* __restrict__ h, float* __restrict__ agg,
    float* __restrict__ cnt, int E)
{
    const int lane = threadIdx.x & 63;
    const int wave = (blockIdx.x * blockDim.x + threadIdx.x) >> 6;
    const int nwaves = (gridDim.x * blockDim.x) >> 6;
    for (int e = wave; e < E; e += nwaves) {
        const int s = src[e];
        const int d = dst[e];
        const float v = h[(size_t)s * 64 + lane];
        atomicAdd(&agg[(size_t)d * 64 + lane], v);
        if (cnt != nullptr && lane == 0) atomicAdd(&cnt[d], 1.0f);
    }
}

// out = PReLU( (agg/deg) @ wl^T + bl + hin @ wr^T , a ) + x0 @ wskip^T + bskip
__global__ __launch_bounds__(256) void dense_kernel(
    const float* __restrict__ agg, const float* __restrict__ cnt,
    const float* __restrict__ hin, const float* __restrict__ x0,
    const float* __restrict__ wl, const float* __restrict__ bl,
    const float* __restrict__ wr, const float* __restrict__ wskip,
    const float* __restrict__ bskip, const float* __restrict__ aprelu,
    float* __restrict__ out, int n)
{
    // weights transposed in LDS: wT[k*64+d] -> lane d reads bank d%32 (2-way, free)
    __shared__ float wlT[64 * 64];
    __shared__ float wrT[64 * 64];
    __shared__ float wsT[64 * 64];
    __shared__ float blS[64], bsS[64], aS[64];
    __shared__ float aggS[4][64], hS[4][64], xS[4][64];

    const int tid = threadIdx.x;
    for (int i = tid; i < 64 * 64; i += 256) {
        const int k = i >> 6, d = i & 63;
        wlT[i] = wl[d * 64 + k];
        wrT[i] = wr[d * 64 + k];
        wsT[i] = wskip[d * 64 + k];
    }
    if (tid < 64) { blS[tid] = bl[tid]; bsS[tid] = bskip[tid]; aS[tid] = aprelu[tid]; }
    __syncthreads();

    const int d  = tid & 63;   // output feature (lane)
    const int ln = tid >> 6;   // local node 0..3 (one wave per node)

    const int ngroups = (n + 3) >> 2;
    for (int g = blockIdx.x; g < ngroups; g += gridDim.x) {
        const int gn = (g << 2) + ln;
        if (gn < n) {
            const float c = cnt[gn];                 // broadcast within wave
            const float inv = 1.0f / fmaxf(c, 1.0f);
            aggS[ln][d] = agg[(size_t)gn * 64 + d] * inv;
            hS[ln][d]   = hin[(size_t)gn * 64 + d];
            xS[ln][d]   = x0[(size_t)gn * 64 + d];
        }
        __syncthreads();
        if (gn < n) {
            float s1 = 0.f, s2 = 0.f, s3 = 0.f;
#pragma unroll
            for (int k = 0; k < 64; k++) {
                s1 += aggS[ln][k] * wlT[k * 64 + d];   // LDS broadcast * 2-way
                s2 += hS[ln][k]   * wrT[k * 64 + d];
                s3 += xS[ln][k]   * wsT[k * 64 + d];
            }
            float o = s1 + blS[d] + s2;
            o = (o >= 0.f) ? o : aS[d] * o;
            o += s3 + bsS[d];
            out[(size_t)gn * 64 + d] = o;
        }
        __syncthreads();
    }
}

extern "C" void kernel_launch(void* const* d_in, const int* in_sizes, int n_in,
                              void* d_out, int out_size, void* d_ws, size_t ws_size,
                              hipStream_t stream)
{
    const float* x   = (const float*)d_in[0];
    const int*   ei  = (const int*)d_in[1];
    const float* wl0 = (const float*)d_in[2];
    const float* bl0 = (const float*)d_in[3];
    const float* wr0 = (const float*)d_in[4];
    const float* ws0 = (const float*)d_in[5];
    const float* bs0 = (const float*)d_in[6];
    const float* a0  = (const float*)d_in[7];
    const float* wl1 = (const float*)d_in[8];
    const float* bl1 = (const float*)d_in[9];
    const float* wr1 = (const float*)d_in[10];
    const float* ws1 = (const float*)d_in[11];
    const float* bs1 = (const float*)d_in[12];
    const float* a1  = (const float*)d_in[13];

    const int E = in_sizes[1] / 2;
    const int n = in_sizes[0] / 64;
    const int* src = ei;
    const int* dst = ei + E;

    float* agg = (float*)d_ws;                 // n*64 floats
    float* h1  = agg + (size_t)n * 64;         // n*64 floats
    float* cnt = h1 + (size_t)n * 64;          // n floats

    hipMemsetAsync(agg, 0, (size_t)n * 64 * sizeof(float), stream);
    hipMemsetAsync(cnt, 0, (size_t)n * sizeof(float), stream);

    const dim3 sblk(256), sgrid(8192);
    const dim3 dblk(256), dgrid(2048);

    // Layer 0: aggregate x, compute h1
    scatter_kernel<<<sgrid, sblk, 0, stream>>>(src, dst, x, agg, cnt, E);
    dense_kernel<<<dgrid, dblk, 0, stream>>>(agg, cnt, x, x,
                                             wl0, bl0, wr0, ws0, bs0, a0, h1, n);

    // Layer 1: aggregate h1, compute output
    hipMemsetAsync(agg, 0, (size_t)n * 64 * sizeof(float), stream);
    scatter_kernel<<<sgrid, sblk, 0, stream>>>(src, dst, h1, agg, nullptr, E);
    dense_kernel<<<dgrid, dblk, 0, stream>>>(agg, cnt, h1, x,
                                             wl1, bl1, wr1, ws1, bs1, a1, (float*)d_out, n);
}

// Round 2
// 1059.577 us; speedup vs baseline: 1.1555x; 1.1555x over previous
//
#include <hip/hip_runtime.h>

// HeteroGraphSage: 2-layer SAGEConv(mean) + PReLU + input-skip.
// N=100000, IN=D=64, E=1600000, fp32.
// Strategy: CSR build (hist/scan/fill, int atomics only) then per-layer
// fused gather+dense kernel. Gather: wave per node, lane=feature, src ids
// via scalar loads (wave-uniform), coalesced 256B feature reads (L2/L3 hot).
// Dense: lane=node, wave owns 16 output dims; weights via scalar s_loads
// (readfirstlane-forced uniform index) -> v_fma with SGPR operand.

#define NN 100000
#define EE 1600000

__global__ __launch_bounds__(256) void hist_kernel(
    const int* __restrict__ dst, int* __restrict__ deg, int E)
{
    int i = blockIdx.x * blockDim.x + threadIdx.x;
    int stride = gridDim.x * blockDim.x;
    for (int e = i; e < E; e += stride) atomicAdd(&deg[dst[e]], 1);
}

__global__ __launch_bounds__(256) void bsum_kernel(
    const int* __restrict__ deg, int* __restrict__ bsum, int n)
{
    __shared__ int sh[256];
    int i = blockIdx.x * 256 + threadIdx.x;
    sh[threadIdx.x] = (i < n) ? deg[i] : 0;
    __syncthreads();
    for (int s = 128; s > 0; s >>= 1) {
        if (threadIdx.x < s) sh[threadIdx.x] += sh[threadIdx.x + s];
        __syncthreads();
    }
    if (threadIdx.x == 0) bsum[blockIdx.x] = sh[0];
}

__global__ __launch_bounds__(512) void scanb_kernel(
    const int* __restrict__ bsum, int* __restrict__ bsumX, int nb)
{
    __shared__ int sh[512];
    int tid = threadIdx.x;
    int v = (tid < nb) ? bsum[tid] : 0;
    sh[tid] = v;
    __syncthreads();
    for (int off = 1; off < 512; off <<= 1) {
        int t = (tid >= off) ? sh[tid - off] : 0;
        __syncthreads();
        sh[tid] += t;
        __syncthreads();
    }
    bsumX[tid] = sh[tid] - v;   // exclusive
}

__global__ __launch_bounds__(256) void rowstart_kernel(
    const int* __restrict__ deg, const int* __restrict__ bsumX,
    int* __restrict__ rowStart, int n)
{
    __shared__ int sh[256];
    int tid = threadIdx.x;
    int i = blockIdx.x * 256 + tid;
    int v = (i < n) ? deg[i] : 0;
    sh[tid] = v;
    __syncthreads();
    for (int off = 1; off < 256; off <<= 1) {
        int t = (tid >= off) ? sh[tid - off] : 0;
        __syncthreads();
        sh[tid] += t;
        __syncthreads();
    }
    if (i < n) rowStart[i] = sh[tid] - v + bsumX[blockIdx.x];
}

__global__ __launch_bounds__(256) void fill_kernel(
    const int* __restrict__ src, const int* __restrict__ dst,
    const int* __restrict__ rowStart, int* __restrict__ cursor,
    int* __restrict__ srcSorted, int E)
{
    int i = blockIdx.x * blockDim.x + threadIdx.x;
    int stride = gridDim.x * blockDim.x;
    for (int e = i; e < E; e += stride) {
        int d = dst[e];
        int pos = rowStart[d] + atomicAdd(&cursor[d], 1);
        srcSorted[pos] = src[e];
    }
}

// out = PReLU( (mean agg of hin over in-edges) @ wl^T + bl + hin @ wr^T , a )
//       + x0 @ wskip^T + bskip
__global__ __launch_bounds__(256) void layer_kernel(
    const int* __restrict__ rowStart, const int* __restrict__ deg,
    const int* __restrict__ srcSorted,
    const float* __restrict__ hin, const float* __restrict__ x0,
    const float* __restrict__ wl, const float* __restrict__ bl,
    const float* __restrict__ wr, const float* __restrict__ wskip,
    const float* __restrict__ bskip, const float* __restrict__ aprelu,
    float* __restrict__ out, int n)
{
    // +2 pad: lane stride 66 dwords -> banks (2*lane+c)%32, 2-way = free
    __shared__ float agg_s[64][66];
    __shared__ float h_s[64][66];
    __shared__ float x_s[64][66];
    float (*out_s)[66] = agg_s;   // reuse after compute (sync-guarded)

    const int tid  = threadIdx.x;
    const int lane = tid & 63;
    const int wvu  = __builtin_amdgcn_readfirstlane(tid >> 6);  // 0..3, SGPR

    const int tileBase = blockIdx.x * 64;

    // ---- Phase A: gather (wave per node, 16 nodes per wave, lane=feature)
    for (int i = 0; i < 16; i++) {
        const int nl = wvu * 16 + i;
        const int node = tileBase + nl;
        if (node < n) {
            const int rs = rowStart[node];
            const int dg = deg[node];
            float acc = 0.f;
            int j = 0;
            for (; j + 4 <= dg; j += 4) {
                const int s0 = srcSorted[rs + j];
                const int s1 = srcSorted[rs + j + 1];
                const int s2 = srcSorted[rs + j + 2];
                const int s3 = srcSorted[rs + j + 3];
                const float v0 = hin[(size_t)s0 * 64 + lane];
                const float v1 = hin[(size_t)s1 * 64 + lane];
                const float v2 = hin[(size_t)s2 * 64 + lane];
                const float v3 = hin[(size_t)s3 * 64 + lane];
                acc += v0 + v1 + v2 + v3;
            }
            for (; j < dg; j++) {
                const int s = srcSorted[rs + j];
                acc += hin[(size_t)s * 64 + lane];
            }
            const float inv = 1.0f / fmaxf((float)dg, 1.0f);
            agg_s[nl][lane] = acc * inv;
            h_s[nl][lane]   = hin[(size_t)node * 64 + lane];
            x_s[nl][lane]   = x0[(size_t)node * 64 + lane];
        } else {
            agg_s[nl][lane] = 0.f;
            h_s[nl][lane]   = 0.f;
            x_s[nl][lane]   = 0.f;
        }
    }
    __syncthreads();

    // ---- Phase B: dense. lane = node (64 nodes), this wave covers
    // output dims d in [wvu*16, wvu*16+16). Weight indices wave-uniform ->
    // scalar loads feeding v_fma.
    float acc1[16], acc2[16], acc3[16];
#pragma unroll
    for (int dd = 0; dd < 16; dd++) { acc1[dd] = 0.f; acc2[dd] = 0.f; acc3[dd] = 0.f; }

#pragma unroll
    for (int kc = 0; kc < 4; kc++) {
        float ak[16], hk[16], xk[16];
#pragma unroll
        for (int k = 0; k < 16; k++) {
            ak[k] = agg_s[lane][kc * 16 + k];
            hk[k] = h_s[lane][kc * 16 + k];
            xk[k] = x_s[lane][kc * 16 + k];
        }
#pragma unroll
        for (int dd = 0; dd < 16; dd++) {
            const int d = wvu * 16 + dd;
            const float* wlr = wl    + d * 64 + kc * 16;
            const float* wrr = wr    + d * 64 + kc * 16;
            const float* wsr = wskip + d * 64 + kc * 16;
#pragma unroll
            for (int k = 0; k < 16; k++) {
                acc1[dd] += ak[k] * wlr[k];
                acc2[dd] += hk[k] * wrr[k];
                acc3[dd] += xk[k] * wsr[k];
            }
        }
    }

    __syncthreads();   // everyone done reading agg_s before alias-write

#pragma unroll
    for (int dd = 0; dd < 16; dd++) {
        const int d = wvu * 16 + dd;
        float z = acc1[dd] + acc2[dd] + bl[d];
        z = (z >= 0.f) ? z : aprelu[d] * z;
        out_s[lane][d] = z + acc3[dd] + bskip[d];
    }
    __syncthreads();

    // coalesced global write
    for (int i = tid; i < 64 * 64; i += 256) {
        const int nl = i >> 6, d = i & 63;
        const int node = tileBase + nl;
        if (node < n) out[(size_t)node * 64 + d] = out_s[nl][d];
    }
}

extern "C" void kernel_launch(void* const* d_in, const int* in_sizes, int n_in,
                              void* d_out, int out_size, void* d_ws, size_t ws_size,
                              hipStream_t stream)
{
    const float* x   = (const float*)d_in[0];
    const int*   ei  = (const int*)d_in[1];
    const float* wl0 = (const float*)d_in[2];
    const float* bl0 = (const float*)d_in[3];
    const float* wr0 = (const float*)d_in[4];
    const float* ws0 = (const float*)d_in[5];
    const float* bs0 = (const float*)d_in[6];
    const float* a0  = (const float*)d_in[7];
    const float* wl1 = (const float*)d_in[8];
    const float* bl1 = (const float*)d_in[9];
    const float* wr1 = (const float*)d_in[10];
    const float* ws1 = (const float*)d_in[11];
    const float* bs1 = (const float*)d_in[12];
    const float* a1  = (const float*)d_in[13];

    const int n = in_sizes[0] / 64;
    const int E = in_sizes[1] / 2;
    const int* src = ei;
    const int* dst = ei + E;

    int* deg       = (int*)d_ws;
    int* cursor    = deg + n;
    int* rowStart  = cursor + n;
    int* bsum      = rowStart + n;
    int* bsumX     = bsum + 512;
    int* srcSorted = bsumX + 512;
    float* h1      = (float*)(srcSorted + E);

    hipMemsetAsync(deg, 0, (size_t)n * sizeof(int), stream);
    hipMemsetAsync(cursor, 0, (size_t)n * sizeof(int), stream);

    const int nb = (n + 255) / 256;   // 391 <= 512

    hist_kernel<<<2048, 256, 0, stream>>>(dst, deg, E);
    bsum_kernel<<<nb, 256, 0, stream>>>(deg, bsum, n);
    scanb_kernel<<<1, 512, 0, stream>>>(bsum, bsumX, nb);
    rowstart_kernel<<<nb, 256, 0, stream>>>(deg, bsumX, rowStart, n);
    fill_kernel<<<2048, 256, 0, stream>>>(src, dst, rowStart, cursor, srcSorted, E);

    const int ntiles = (n + 63) / 64;

    // Layer 0: hin = x
    layer_kernel<<<ntiles, 256, 0, stream>>>(rowStart, deg, srcSorted,
        x, x, wl0, bl0, wr0, ws0, bs0, a0, h1, n);
    // Layer 1: hin = h1
    layer_kernel<<<ntiles, 256, 0, stream>>>(rowStart, deg, srcSorted,
        h1, x, wl1, bl1, wr1, ws1, bs1, a1, (float*)d_out, n);
}